// Round 11
// baseline (336.175 us; speedup 1.0000x reference)
//
#include <hip/hip_runtime.h>
#include <hip/hip_bf16.h>
#include <math.h>

// Problem constants (fixed by setup_inputs)
#define Bq 8
#define Nq 2048
#define Pq 64
#define Dq 128
#define Kq 16
#define BNq (Bq * Nq)   // 16384 points total

typedef unsigned short u16;
typedef __bf16 bf16x8v __attribute__((ext_vector_type(8)));
typedef float f32x4v __attribute__((ext_vector_type(4)));

__device__ __forceinline__ u16 f2b(float f) {
    return __builtin_bit_cast(u16, (__bf16)f);      // RNE
}
__device__ __forceinline__ float b2f(u16 u) {
    return (float)__builtin_bit_cast(__bf16, u);
}

// Wt element offsets (all stored transposed bf16: Wt[n][k]).
// FUSION: GAM1 slot holds W~ = Wdel2@Wgam1; PHI/PSI/DPT2 slots hold
// Wphi@Wgam1 / Wpsi@Wgam1 / Wdpt2@Wgam1 (composed in prep_mm).
#define OFF_DEL2 0
#define OFF_GAM1 16384
#define OFF_GAM2 32768
#define OFF_FC1  49152
#define OFF_PHI  57344
#define OFF_PSI  73728
#define OFF_ALF  90112
#define OFF_DPT1 106496
#define OFF_DPT2 122880
#define WT_TOTAL 139264

// ---------------------------------------------------------------------------
// Kernel 0a: direct transpose+convert for the 5 uncomposed weights.
// ---------------------------------------------------------------------------
__global__ __launch_bounds__(256) void prep_direct(
    const float* __restrict__ Wdel2, const float* __restrict__ Wgam2,
    const float* __restrict__ Wfc1, const float* __restrict__ Walpha,
    const float* __restrict__ Wdpt1, u16* __restrict__ Wt) {
    int idx = blockIdx.x * 256 + threadIdx.x;       // 0..73727
    if (idx < 16384) {
        int n = idx >> 7, k = idx & 127;
        Wt[OFF_DEL2 + idx] = f2b(Wdel2[k * 128 + n]);
    } else if (idx < 32768) {
        int r = idx - 16384, n = r >> 7, k = r & 127;
        Wt[OFF_GAM2 + r] = f2b(Wgam2[k * 128 + n]);
    } else if (idx < 40960) {
        int r = idx - 32768, n = r >> 6, k = r & 63;
        Wt[OFF_FC1 + r] = f2b(Wfc1[k * 128 + n]);
    } else if (idx < 57344) {
        int r = idx - 40960, n = r >> 7, k = r & 127;
        Wt[OFF_ALF + r] = f2b(Walpha[k * 128 + n]);
    } else if (idx < 73728) {
        int r = idx - 57344, n = r >> 7, k = r & 127;
        Wt[OFF_DPT1 + r] = f2b(Wdpt1[k * 128 + n]);
    }
}

// ---------------------------------------------------------------------------
// Kernel 0b: composed weights  Wt[X] = (A @ Wgam1)^T in bf16.
// 32 blocks x 256 threads; Wgam1 staged in LDS (64 KB); fp32 accumulate.
// ---------------------------------------------------------------------------
__global__ __launch_bounds__(256) void prep_mm(
    const float* __restrict__ Wdel2, const float* __restrict__ Wphi,
    const float* __restrict__ Wpsi, const float* __restrict__ Wdpt2,
    const float* __restrict__ Wgam1, u16* __restrict__ Wt) {
    __shared__ float sB[128 * 128];                 // 64 KB
    for (int i = threadIdx.x; i < 16384; i += 256) sB[i] = Wgam1[i];
    __syncthreads();
    const int mat = blockIdx.x >> 3;
    const int chunk = blockIdx.x & 7;
    const float* A = (mat == 0) ? Wdel2 : (mat == 1) ? Wphi : (mat == 2) ? Wpsi : Wdpt2;
    const int OFF = (mat == 0) ? OFF_GAM1 : (mat == 1) ? OFF_PHI : (mat == 2) ? OFF_PSI : OFF_DPT2;
    const int o0 = chunk * 2048 + threadIdx.x * 8;  // 8 outputs: same n, k0..k0+7
    const int n = o0 >> 7, k0 = o0 & 127;
#pragma unroll
    for (int kk = 0; kk < 8; ++kk) {
        const float* Ar = A + (size_t)(k0 + kk) * 128;
        float s = 0.f;
        for (int j = 0; j < 128; j += 4) {
            float4 a4 = *(const float4*)(Ar + j);
            s = fmaf(a4.x, sB[(j + 0) * 128 + n], s);
            s = fmaf(a4.y, sB[(j + 1) * 128 + n], s);
            s = fmaf(a4.z, sB[(j + 2) * 128 + n], s);
            s = fmaf(a4.w, sB[(j + 3) * 128 + n], s);
        }
        Wt[OFF + n * 128 + k0 + kk] = f2b(s);
    }
}

// ---------------------------------------------------------------------------
// Kernel 0c: fused gam1-input bias  bGt[n] = bgam1 + (bdel2+bdpt2)@Wgam1.
// ---------------------------------------------------------------------------
__global__ void prep_bias(const float* __restrict__ bgam1,
                          const float* __restrict__ bdel2,
                          const float* __restrict__ bdpt2,
                          const float* __restrict__ Wgam1,
                          float* __restrict__ bGt) {
    int n = threadIdx.x;                            // 128 threads
    float s = bgam1[n];
    for (int k = 0; k < 128; ++k)
        s = fmaf(bdel2[k] + bdpt2[k], Wgam1[k * 128 + n], s);
    bGt[n] = s;
}

// ---------------------------------------------------------------------------
// Kernel 1 (v2): exact kNN. 512 blocks x 256 threads. (measured-good)
// ---------------------------------------------------------------------------
__global__ __launch_bounds__(256) void knn_kernel(const float* __restrict__ x,
                                                  int* __restrict__ knn) {
    __shared__ float4 sx[Nq];                       // 32 KB
    __shared__ float sLd[32][8][17];
    __shared__ int   sLi[32][8][17];
    const int b = blockIdx.x >> 6;
    const int q0 = (blockIdx.x & 63) * 32;
    const float* xb = x + b * Nq * 3;
    for (int j = threadIdx.x; j < Nq; j += 256) {
        float x0 = xb[j * 3 + 0], x1 = xb[j * 3 + 1], x2 = xb[j * 3 + 2];
        // replicate jnp.sum(x*x): no fma contraction
        float n2 = __fadd_rn(__fadd_rn(__fmul_rn(x0, x0), __fmul_rn(x1, x1)),
                             __fmul_rn(x2, x2));
        sx[j] = make_float4(x0, x1, x2, n2);
    }
    __syncthreads();
    const int q = threadIdx.x & 31;
    const int sub = threadIdx.x >> 5;
    const float4 qv = sx[q0 + q];
    float bd[Kq];
    int bj[Kq];
#pragma unroll
    for (int s = 0; s < Kq; ++s) { bd[s] = INFINITY; bj[s] = 0; }
    const int j0 = sub * 256;
    for (int i = 0; i < 256; ++i) {
        const int j = j0 + i;
        float4 p = sx[j];
        float dot = __fadd_rn(__fadd_rn(__fmul_rn(qv.x, p.x), __fmul_rn(qv.y, p.y)),
                              __fmul_rn(qv.z, p.z));
        float d = __fsub_rn(__fadd_rn(qv.w, p.w), __fmul_rn(2.0f, dot));
        if (d < bd[Kq - 1]) {                       // strict <: stable
            bd[Kq - 1] = d; bj[Kq - 1] = j;
#pragma unroll
            for (int s = Kq - 1; s >= 1; --s) {
                if (bd[s] < bd[s - 1]) {
                    float td = bd[s]; bd[s] = bd[s - 1]; bd[s - 1] = td;
                    int tj = bj[s]; bj[s] = bj[s - 1]; bj[s - 1] = tj;
                }
            }
        }
    }
#pragma unroll
    for (int s = 0; s < Kq; ++s) { sLd[q][sub][s] = bd[s]; sLi[q][sub][s] = bj[s]; }
    __syncthreads();
    if (threadIdx.x < 32) {
        const int mq = threadIdx.x;
        int pos[8]; float hd[8]; int hi[8];
#pragma unroll
        for (int s = 0; s < 8; ++s) {
            pos[s] = 1; hd[s] = sLd[mq][s][0]; hi[s] = sLi[mq][s][0];
        }
        int* o = knn + (b * Nq + q0 + mq) * Kq;
#pragma unroll
        for (int oi = 0; oi < Kq; ++oi) {
            float bdv = hd[0]; int biv = hi[0]; int bs = 0;
#pragma unroll
            for (int s = 1; s < 8; ++s) {
                bool take = (hd[s] < bdv) || (hd[s] == bdv && hi[s] < biv);
                if (take) { bdv = hd[s]; biv = hi[s]; bs = s; }
            }
            o[oi] = biv;
#pragma unroll
            for (int s = 0; s < 8; ++s) {           // static-index update
                if (s == bs) {
                    int pp = pos[s] < Kq ? pos[s] : (Kq - 1);
                    bool ok = pos[s] < Kq;
                    hd[s] = ok ? sLd[mq][s][pp] : INFINITY;
                    hi[s] = ok ? sLi[mq][s][pp] : 0x7fffffff;
                    pos[s]++;
                }
            }
        }
    }
}

// ---------------------------------------------------------------------------
// Shared MFMA helpers (feat kernel). XOR swizzle byte ^= (row&7)<<4.
// ---------------------------------------------------------------------------
template <int BYTES, int ROWBYTES>
__device__ __forceinline__ void stageW(const u16* __restrict__ src,
                                       u16* __restrict__ sW, int t) {
#pragma unroll
    for (int c = 0; c < BYTES / 4096; ++c) {
        int lin = c * 4096 + t * 16;
        int n = lin / ROWBYTES;
        int o = lin % ROWBYTES;
        bf16x8v v = *(const bf16x8v*)((const char*)src + lin);
        *(bf16x8v*)((char*)sW + n * ROWBYTES + (o ^ ((n & 7) << 4))) = v;
    }
}

__device__ __forceinline__ void mfma_k128(const u16* __restrict__ sA,
                                          const u16* __restrict__ sW,
                                          int colbase, int lane,
                                          f32x4v (&acc)[4][2]) {
    const int kg = lane >> 4;
    const int l15 = lane & 15;
#pragma unroll
    for (int ks = 0; ks < 4; ++ks) {
        bf16x8v a[4], bfr[2];
#pragma unroll
        for (int m = 0; m < 4; ++m) {
            int row = m * 16 + l15;
            int o = (ks * 64 + kg * 16) ^ ((row & 7) << 4);
            a[m] = *(const bf16x8v*)((const char*)sA + row * 256 + o);
        }
#pragma unroll
        for (int nt = 0; nt < 2; ++nt) {
            int n = colbase + nt * 16 + l15;
            int o = (ks * 64 + kg * 16) ^ ((n & 7) << 4);
            bfr[nt] = *(const bf16x8v*)((const char*)sW + n * 256 + o);
        }
#pragma unroll
        for (int m = 0; m < 4; ++m)
#pragma unroll
            for (int nt = 0; nt < 2; ++nt)
                acc[m][nt] = __builtin_amdgcn_mfma_f32_16x16x32_bf16(a[m], bfr[nt], acc[m][nt], 0, 0, 0);
    }
}

__device__ __forceinline__ void mfma_k64(const u16* __restrict__ sA,
                                         const u16* __restrict__ sW,
                                         int colbase, int lane,
                                         f32x4v (&acc)[4][2]) {
    const int kg = lane >> 4;
    const int l15 = lane & 15;
#pragma unroll
    for (int ks = 0; ks < 2; ++ks) {
        bf16x8v a[4], bfr[2];
#pragma unroll
        for (int m = 0; m < 4; ++m) {
            int row = m * 16 + l15;
            int o = (ks * 64 + kg * 16) ^ ((row & 7) << 4);
            a[m] = *(const bf16x8v*)((const char*)sA + row * 128 + o);
        }
#pragma unroll
        for (int nt = 0; nt < 2; ++nt) {
            int n = colbase + nt * 16 + l15;
            int o = (ks * 64 + kg * 16) ^ ((n & 7) << 4);
            bfr[nt] = *(const bf16x8v*)((const char*)sW + n * 128 + o);
        }
#pragma unroll
        for (int m = 0; m < 4; ++m)
#pragma unroll
            for (int nt = 0; nt < 2; ++nt)
                acc[m][nt] = __builtin_amdgcn_mfma_f32_16x16x32_bf16(a[m], bfr[nt], acc[m][nt], 0, 0, 0);
    }
}

// ---------------------------------------------------------------------------
// Kernel 2 (MFMA): per-point features. Same 6-stage structure as round 3,
// but psi/base stages now use COMPOSED weights and emit psiG/baseG (bf16):
//   psiG = f@(Wpsi@Wgam1); baseG = f@(Wphi@Wgam1) + t1@(Wdpt2@Wgam1)
// (bdpt2's contribution is folded into bGt, so dpt2G stage has no bias.)
// ---------------------------------------------------------------------------
__global__ __launch_bounds__(256, 2) void feat_kernel(
    const float* __restrict__ in_f, const u16* __restrict__ Wt,
    const float* __restrict__ bfc1, const float* __restrict__ bdpt1,
    u16* __restrict__ baseGB, u16* __restrict__ psiGB, u16* __restrict__ alphaB) {
    __shared__ __align__(16) u16 sIn[64 * 64];      // 8 KB
    __shared__ __align__(16) u16 sF[64 * 128];      // 16 KB
    __shared__ __align__(16) u16 sW[128 * 128];     // 32 KB
    const int t = threadIdx.x;
    const int lane = t & 63;
    const int w = t >> 6;
    const int kg = lane >> 4;
    const int l15 = lane & 15;
    const int p0 = blockIdx.x * 64;

    {
        const int r = t >> 2;
        const int c0 = (t & 3) * 16;
        const float* src = &in_f[(size_t)(p0 + r) * 64 + c0];
        float4 v0 = *(const float4*)(src + 0);
        float4 v1 = *(const float4*)(src + 4);
        float4 v2 = *(const float4*)(src + 8);
        float4 v3 = *(const float4*)(src + 12);
        bf16x8v lo, hi;
        lo[0] = (__bf16)v0.x; lo[1] = (__bf16)v0.y; lo[2] = (__bf16)v0.z; lo[3] = (__bf16)v0.w;
        lo[4] = (__bf16)v1.x; lo[5] = (__bf16)v1.y; lo[6] = (__bf16)v1.z; lo[7] = (__bf16)v1.w;
        hi[0] = (__bf16)v2.x; hi[1] = (__bf16)v2.y; hi[2] = (__bf16)v2.z; hi[3] = (__bf16)v2.w;
        hi[4] = (__bf16)v3.x; hi[5] = (__bf16)v3.y; hi[6] = (__bf16)v3.z; hi[7] = (__bf16)v3.w;
        const int swz = (r & 7) << 4;
        *(bf16x8v*)((char*)sIn + r * 128 + ((c0 * 2) ^ swz)) = lo;
        *(bf16x8v*)((char*)sIn + r * 128 + (((c0 + 8) * 2) ^ swz)) = hi;
    }

    f32x4v acc[4][2], accPhi[4][2];

    // ---- fc1: f = in_f @ Wfc1 + b ----
    {
        float bv0 = bfc1[w * 32 + l15];
        float bv1 = bfc1[w * 32 + 16 + l15];
#pragma unroll
        for (int m = 0; m < 4; ++m) { acc[m][0] = f32x4v{bv0, bv0, bv0, bv0}; acc[m][1] = f32x4v{bv1, bv1, bv1, bv1}; }
    }
    stageW<16384, 128>(Wt + OFF_FC1, sW, t);
    __syncthreads();
    mfma_k64(sIn, sW, w * 32, lane, acc);

#pragma unroll
    for (int m = 0; m < 4; ++m)
#pragma unroll
        for (int nt = 0; nt < 2; ++nt)
#pragma unroll
            for (int rr = 0; rr < 4; ++rr) {
                int row = m * 16 + kg * 4 + rr;
                int col = w * 32 + nt * 16 + l15;
                *(__bf16*)((char*)sF + row * 256 + ((col * 2) ^ ((row & 7) << 4))) = (__bf16)acc[m][nt][rr];
            }

    // ---- phiG = f @ (Wphi@Wgam1) (kept in regs) ----
#pragma unroll
    for (int m = 0; m < 4; ++m) { accPhi[m][0] = f32x4v{0, 0, 0, 0}; accPhi[m][1] = f32x4v{0, 0, 0, 0}; }
    __syncthreads();
    stageW<32768, 256>(Wt + OFF_PHI, sW, t);
    __syncthreads();
    mfma_k128(sF, sW, w * 32, lane, accPhi);

    // ---- psiG = f @ (Wpsi@Wgam1) -> bf16 global ----
#pragma unroll
    for (int m = 0; m < 4; ++m) { acc[m][0] = f32x4v{0, 0, 0, 0}; acc[m][1] = f32x4v{0, 0, 0, 0}; }
    __syncthreads();
    stageW<32768, 256>(Wt + OFF_PSI, sW, t);
    __syncthreads();
    mfma_k128(sF, sW, w * 32, lane, acc);
#pragma unroll
    for (int m = 0; m < 4; ++m)
#pragma unroll
        for (int nt = 0; nt < 2; ++nt)
#pragma unroll
            for (int rr = 0; rr < 4; ++rr) {
                int row = m * 16 + kg * 4 + rr;
                int col = w * 32 + nt * 16 + l15;
                psiGB[(size_t)(p0 + row) * 128 + col] = f2b(acc[m][nt][rr]);
            }

    // ---- alpha = f @ Walpha -> bf16 global ----
#pragma unroll
    for (int m = 0; m < 4; ++m) { acc[m][0] = f32x4v{0, 0, 0, 0}; acc[m][1] = f32x4v{0, 0, 0, 0}; }
    __syncthreads();
    stageW<32768, 256>(Wt + OFF_ALF, sW, t);
    __syncthreads();
    mfma_k128(sF, sW, w * 32, lane, acc);
#pragma unroll
    for (int m = 0; m < 4; ++m)
#pragma unroll
        for (int nt = 0; nt < 2; ++nt)
#pragma unroll
            for (int rr = 0; rr < 4; ++rr) {
                int row = m * 16 + kg * 4 + rr;
                int col = w * 32 + nt * 16 + l15;
                alphaB[(size_t)(p0 + row) * 128 + col] = f2b(acc[m][nt][rr]);
            }

    // ---- t1 = relu(f @ Wdpt1 + b) ----
    {
        float bv0 = bdpt1[w * 32 + l15];
        float bv1 = bdpt1[w * 32 + 16 + l15];
#pragma unroll
        for (int m = 0; m < 4; ++m) { acc[m][0] = f32x4v{bv0, bv0, bv0, bv0}; acc[m][1] = f32x4v{bv1, bv1, bv1, bv1}; }
    }
    __syncthreads();
    stageW<32768, 256>(Wt + OFF_DPT1, sW, t);
    __syncthreads();
    mfma_k128(sF, sW, w * 32, lane, acc);
    __syncthreads();
#pragma unroll
    for (int m = 0; m < 4; ++m)
#pragma unroll
        for (int nt = 0; nt < 2; ++nt)
#pragma unroll
            for (int rr = 0; rr < 4; ++rr) {
                int row = m * 16 + kg * 4 + rr;
                int col = w * 32 + nt * 16 + l15;
                *(__bf16*)((char*)sF + row * 256 + ((col * 2) ^ ((row & 7) << 4))) =
                    (__bf16)fmaxf(acc[m][nt][rr], 0.f);
            }

    // ---- baseG = phiG + t1 @ (Wdpt2@Wgam1) -> bf16 global (no bias) ----
#pragma unroll
    for (int m = 0; m < 4; ++m) { acc[m][0] = f32x4v{0, 0, 0, 0}; acc[m][1] = f32x4v{0, 0, 0, 0}; }
    __syncthreads();
    stageW<32768, 256>(Wt + OFF_DPT2, sW, t);
    __syncthreads();
    mfma_k128(sF, sW, w * 32, lane, acc);
#pragma unroll
    for (int m = 0; m < 4; ++m)
#pragma unroll
        for (int nt = 0; nt < 2; ++nt)
#pragma unroll
            for (int rr = 0; rr < 4; ++rr) {
                int row = m * 16 + kg * 4 + rr;
                int col = w * 32 + nt * 16 + l15;
                baseGB[(size_t)(p0 + row) * 128 + col] = f2b(acc[m][nt][rr] + accPhi[m][nt][rr]);
            }
}

// ---------------------------------------------------------------------------
// Kernel 3 (v8, FUSED): r5-proven skeleton (1024 x 512, __syncthreads,
// 3 blocks/CU, inline gathers) with the gam1 phase algebraically fused:
//   dual phase: delta = h1@Wdel2 (LDS B), gIn = h1@W~ (reg B), shared A-frags
//   g1 = relu(gIn + baseG[p] - psiG[j])  -> sA; gam2; softmax; out.
// 4 barriers/chunk (r5 had 6), no pre roundtrip. LDS ~53 KB.
// ---------------------------------------------------------------------------
__global__ __launch_bounds__(512, 4) void main_kernel(
    const float* __restrict__ x, const float* __restrict__ in_f,
    const float* __restrict__ Wdel1, const float* __restrict__ bdel1,
    const float* __restrict__ bdel2, const float* __restrict__ bGt,
    const float* __restrict__ bgam2,
    const float* __restrict__ Wfc2, const float* __restrict__ bfc2,
    const u16* __restrict__ baseGB, const u16* __restrict__ psiGB,
    const u16* __restrict__ alphaB, const int* __restrict__ knn,
    const u16* __restrict__ Wt, float* __restrict__ out) {
    __shared__ __align__(16) u16 sWd2[128 * 128];   // 32 KB del2 weights (swz)
    __shared__ __align__(16) u16 sA[64 * 128];      // 16 KB h1 -> g1 (swz)
    __shared__ float sWd1[512];                     // Wdel1 rows + bias at 384
    __shared__ int sIdx[64];
    __shared__ float sY[4][128];

    const int t = threadIdx.x;
    const int lane = t & 63;
    const int w = t >> 6;                            // wave 0..7
    const int kg = lane >> 4;
    const int l15 = lane & 15;
    const int colW = w * 16 + l15;                   // this thread's out column

    const int pbase = blockIdx.x * 16;               // 16 points per block
    const int b = pbase >> 11;
    const int bN = b * Nq;
    const int hr = t >> 3;                           // B-phase row 0..63
    const int hc0 = (t & 7) * 16;                    // B-phase col base

    // ---- prologue: del2 weights -> LDS, Wdel1 -> LDS, W~/gam2 -> regs ----
#pragma unroll
    for (int c = 0; c < 4; ++c) {
        int lin = c * 8192 + t * 16;
        int n = lin >> 8;
        int o = lin & 255;
        bf16x8v v = *(const bf16x8v*)((const char*)(Wt + OFF_DEL2) + lin);
        *(bf16x8v*)((char*)sWd2 + n * 256 + (o ^ ((n & 7) << 4))) = v;
    }
    sWd1[t] = (t < 384) ? Wdel1[t] : bdel1[t - 384];
    bf16x8v wG1[4], wG2[4];
#pragma unroll
    for (int ks = 0; ks < 4; ++ks) {
        size_t off = (size_t)colW * 128 + ks * 32 + kg * 8;
        wG1[ks] = *(const bf16x8v*)(Wt + OFF_GAM1 + off);   // W~ fragments
        wG2[ks] = *(const bf16x8v*)(Wt + OFF_GAM2 + off);
    }
    const float bD = bdel2[colW];
    const float bG1 = bGt[colW];                     // fused gam1-input bias
    const float bG2 = bgam2[colW];
    const float bOq = bfc2[(t & 127) >> 1];
    __syncthreads();                                 // prologue fence

    for (int c = 0; c < 4; ++c) {
        const int p0 = pbase + c * 4;

        // ---- A (t<64): neighbor indices -> LDS ----
        if (t < 64) {
            int p = p0 + (t >> 4);
            sIdx[t] = bN + knn[p * Kq + (t & 15)];
        }

        // ---- B: h1 = relu(diff @ Wdel1 + b) -> sA (inline diff) ----
        {
            const int p = p0 + (hr >> 4);
            const int j = knn[p * Kq + (hr & 15)];
            const float* xq = x + (size_t)p * 3;
            const float* xn = x + (size_t)(bN + j) * 3;
            const float dx = xq[0] - xn[0];
            const float dy = xq[1] - xn[1];
            const float dz = xq[2] - xn[2];
            const int swzB = (hr & 7) << 4;
#pragma unroll
            for (int hh = 0; hh < 2; ++hh) {
                bf16x8v hv;
#pragma unroll
                for (int c4 = 0; c4 < 2; ++c4) {
                    const int cc = hc0 + hh * 8 + c4 * 4;
                    float4 wx = *(const float4*)&sWd1[cc];
                    float4 wy = *(const float4*)&sWd1[128 + cc];
                    float4 wz = *(const float4*)&sWd1[256 + cc];
                    float4 b4 = *(const float4*)&sWd1[384 + cc];
                    hv[c4 * 4 + 0] = (__bf16)fmaxf(fmaf(dz, wz.x, fmaf(dy, wy.x, fmaf(dx, wx.x, b4.x))), 0.f);
                    hv[c4 * 4 + 1] = (__bf16)fmaxf(fmaf(dz, wz.y, fmaf(dy, wy.y, fmaf(dx, wx.y, b4.y))), 0.f);
                    hv[c4 * 4 + 2] = (__bf16)fmaxf(fmaf(dz, wz.z, fmaf(dy, wy.z, fmaf(dx, wx.z, b4.z))), 0.f);
                    hv[c4 * 4 + 3] = (__bf16)fmaxf(fmaf(dz, wz.w, fmaf(dy, wy.w, fmaf(dx, wx.w, b4.w))), 0.f);
                }
                *(bf16x8v*)((char*)sA + hr * 256 + (((hc0 + hh * 8) * 2) ^ swzB)) = hv;
            }
        }
        __syncthreads();                             // bar1: h1 + sIdx ready

        // ---- dual MFMA: delta = h1@Wdel2 (LDS B), gIn = h1@W~ (reg B) ----
        f32x4v accD[4], accG[4];
#pragma unroll
        for (int m = 0; m < 4; ++m) { accD[m] = f32x4v{bD, bD, bD, bD}; accG[m] = f32x4v{bG1, bG1, bG1, bG1}; }
#pragma unroll
        for (int ks = 0; ks < 4; ++ks) {
            bf16x8v bbD;
            {
                int o = (ks * 64 + kg * 16) ^ ((colW & 7) << 4);
                bbD = *(const bf16x8v*)((const char*)sWd2 + colW * 256 + o);
            }
#pragma unroll
            for (int m = 0; m < 4; ++m) {
                int row = m * 16 + l15;
                int o = (ks * 64 + kg * 16) ^ ((row & 7) << 4);
                bf16x8v a = *(const bf16x8v*)((const char*)sA + row * 256 + o);
                accD[m] = __builtin_amdgcn_mfma_f32_16x16x32_bf16(a, bbD, accD[m], 0, 0, 0);
                accG[m] = __builtin_amdgcn_mfma_f32_16x16x32_bf16(a, wG1[ks], accG[m], 0, 0, 0);
            }
        }
        __syncthreads();                             // bar2: h1 reads done

        // ---- g1 = relu(gIn + baseG[p] - psiG[j]) -> sA ----
#pragma unroll
        for (int m = 0; m < 4; ++m) {
            const float bsf = b2f(baseGB[(size_t)(p0 + m) * 128 + colW]);
#pragma unroll
            for (int rr = 0; rr < 4; ++rr) {
                int row = m * 16 + kg * 4 + rr;
                float ps = b2f(psiGB[(size_t)sIdx[row] * 128 + colW]);
                int off = row * 256 + ((colW * 2) ^ ((row & 7) << 4));
                *(__bf16*)((char*)sA + off) = (__bf16)fmaxf(accG[m][rr] + (bsf - ps), 0.f);
            }
        }
        __syncthreads();                             // bar3: g1 ready

        // ---- gam2: gamma = g1 @ Wgam2 + b (reg B) ----
        f32x4v accT[4];
#pragma unroll
        for (int m = 0; m < 4; ++m) accT[m] = f32x4v{bG2, bG2, bG2, bG2};
#pragma unroll
        for (int ks = 0; ks < 4; ++ks) {
#pragma unroll
            for (int m = 0; m < 4; ++m) {
                int row = m * 16 + l15;
                int o = (ks * 64 + kg * 16) ^ ((row & 7) << 4);
                bf16x8v a = *(const bf16x8v*)((const char*)sA + row * 256 + o);
                accT[m] = __builtin_amdgcn_mfma_f32_16x16x32_bf16(a, wG2[ks], accT[m], 0, 0, 0);
            }
        }

        // ---- softmax over k + y (alpha inline) ----
#pragma unroll
        for (int m = 0; m < 4; ++m) {
            float g0 = accT[m][0], g1v = accT[m][1], g2 = accT[m][2], g3 = accT[m][3];
            float mx = fmaxf(fmaxf(g0, g1v), fmaxf(g2, g3));
            mx = fmaxf(mx, __shfl_xor(mx, 16, 64));
            mx = fmaxf(mx, __shfl_xor(mx, 32, 64));
            float m4 = mx * 0.25f;
            float e0 = expf(0.25f * g0 - m4), e1 = expf(0.25f * g1v - m4);
            float e2 = expf(0.25f * g2 - m4), e3 = expf(0.25f * g3 - m4);
            float s = e0 + e1 + e2 + e3;
            s += __shfl_xor(s, 16, 64);
            s += __shfl_xor(s, 32, 64);
            float y = 0.f;
#pragma unroll
            for (int rr = 0; rr < 4; ++rr) {
                int row = m * 16 + kg * 4 + rr;
                float al = b2f(alphaB[(size_t)sIdx[row] * 128 + colW]);
                float ev = (rr == 0) ? e0 : (rr == 1) ? e1 : (rr == 2) ? e2 : e3;
                y = fmaf(ev, al + accD[m][rr], y);
            }
            y += __shfl_xor(y, 16, 64);
            y += __shfl_xor(y, 32, 64);
            if (kg == 0) sY[m][colW] = y / s;
        }
        __syncthreads();                             // bar4: sY ready; sA free

        // ---- out = y @ Wfc2 + b + in_f (all 8 waves, lane-paired) ----
        {
            const int p = t >> 7;                    // 0..3
            const int q = (t & 127) >> 1;
            const int half = t & 1;
            const int gp = p0 + p;
            float a = 0.f;
            const float* wcol = Wfc2 + (half * 64) * 64 + q;
#pragma unroll 16
            for (int d = 0; d < 64; ++d)
                a = fmaf(sY[p][half * 64 + d], wcol[d * 64], a);
            a += __shfl_xor(a, 1, 64);
            if (half == 0)
                out[(size_t)gp * 64 + q] = a + bOq + in_f[(size_t)gp * 64 + q];
        }
    }
}

// ---------------------------------------------------------------------------
extern "C" void kernel_launch(void* const* d_in, const int* in_sizes, int n_in,
                              void* d_out, int out_size, void* d_ws, size_t ws_size,
                              hipStream_t stream) {
    const float* x     = (const float*)d_in[0];
    const float* in_f  = (const float*)d_in[1];
    const float* Wfc1  = (const float*)d_in[2];
    const float* bfc1  = (const float*)d_in[3];
    const float* Wphi  = (const float*)d_in[4];
    const float* Wpsi  = (const float*)d_in[5];
    const float* Walpha= (const float*)d_in[6];
    const float* Wdpt1 = (const float*)d_in[7];
    const float* bdpt1 = (const float*)d_in[8];
    const float* Wdpt2 = (const float*)d_in[9];
    const float* bdpt2 = (const float*)d_in[10];
    const float* Wgam1 = (const float*)d_in[11];
    const float* bgam1 = (const float*)d_in[12];
    const float* Wgam2 = (const float*)d_in[13];
    const float* bgam2 = (const float*)d_in[14];
    const float* Wdel1 = (const float*)d_in[15];
    const float* bdel1 = (const float*)d_in[16];
    const float* Wdel2 = (const float*)d_in[17];
    const float* bdel2 = (const float*)d_in[18];
    const float* Wfc2  = (const float*)d_in[19];
    const float* bfc2  = (const float*)d_in[20];
    float* out = (float*)d_out;

    // ws: baseGB bf16 (4MB) | psiGB bf16 (4MB) | alphaB bf16 (4MB) | knn (1MB)
    //   | Wt (272KB) | bGt f32 (512B)
    u16*   baseGB = (u16*)d_ws;
    u16*   psiGB  = baseGB + (size_t)BNq * Dq;
    u16*   alphaB = psiGB + (size_t)BNq * Dq;
    int*   knn    = (int*)(alphaB + (size_t)BNq * Dq);
    u16*   Wt     = (u16*)(knn + (size_t)BNq * Kq);
    float* bGt    = (float*)(Wt + WT_TOTAL);

    prep_direct<<<288, 256, 0, stream>>>(Wdel2, Wgam2, Wfc1, Walpha, Wdpt1, Wt);
    prep_mm<<<32, 256, 0, stream>>>(Wdel2, Wphi, Wpsi, Wdpt2, Wgam1, Wt);
    prep_bias<<<1, 128, 0, stream>>>(bgam1, bdel2, bdpt2, Wgam1, bGt);
    knn_kernel<<<512, 256, 0, stream>>>(x, knn);
    feat_kernel<<<BNq / 64, 256, 0, stream>>>(in_f, Wt, bfc1, bdpt1,
                                              baseGB, psiGB, alphaB);
    main_kernel<<<BNq / 16, 512, 0, stream>>>(x, in_f, Wdel1, bdel1, bdel2, bGt,
                                              bgam2, Wfc2, bfc2,
                                              baseGB, psiGB, alphaB, knn, Wt, out);
}